// Round 1
// baseline (4341.082 us; speedup 1.0000x reference)
//
#include <hip/hip_runtime.h>
#include <math.h>

// DrugGraphConv: 5000 graphs x 100 nodes x 400 edges, 5 TAGConv(K=2) layers
// DIMS = [74,70,65,60,55,37], gated softmax pooling per graph.
//
// R6 (1.33ms): per-lane packed-W dwordx4 on vmcnt, LDS 64,404B -> 2 blocks/CU.
// Counters: MfmaUtil 0, HBM 0.8%, VALUBusy 66%, Occ 44% (LDS-capped), VGPR 52.
// => VALU-issue + stall bound. Dense FMA issue floor ~0.55ms; 28% of it wasted
// on the (cgrp x nhalf) clamp (512 lane-slots for 400 tasks); ~0.45ms stalls
// from unroll-1 (one iter of W loads in flight, compiler scheduled at VGPR 52).
//
// R7: (a) dense task remap t = cgrp*100+node = tid -> 6.25 active waves
// (waves 0..6), wave 7 skips gblock and goes straight to propagate (gblock and
// propagate both only READ the same buffer -> safe). -12.5% dense issue.
// (b) chunk loop unroll 2 + __launch_bounds__(512,4): two iters of W loads in
// flight, VGPR capped at 128 so 2-block LDS co-residency can't be lost.
// (c) x staging via dwordx4 (1850 loads instead of 7400).

constexpr int NODES  = 100;
constexpr int EDGES  = 400;
constexpr int STRIDE = 76;     // mult of 4: b128 rows conflict-free in 8-lane groups
constexpr int NTHR   = 512;
constexpr int DENSE_TASKS = 4 * NODES;   // 400 (node,cgrp) tasks
constexpr int DENSE_THR   = 448;         // waves 0..6 execute gblock

// packed W: per layer, per (b,cgrp): D_INP rows x CW4 cols, zero-padded.
// sizes: 12*76*20 + 12*72*20 + 12*68*16 + 12*60*16 + 12*56*12 = 68,160 floats
__device__ __align__(16) float g_packW[68160];

struct __align__(16) Smem {
    float bufA[NODES * STRIDE];        // 30,400 B
    float bufB[NODES * STRIDE];        // 30,400 B
    float csr_val[EDGES];              //  1,600 B (nrm[src] per CSR slot)
    unsigned short csr_src[EDGES];     //    800 B (src node ids < 100)
    int   row_start[NODES + 1];        //    404 B
    int   cntg[NODES];                 //    400 B (cnt during setup, gate after)
    float nrm[NODES];                  //    400 B  => 64,404 B (2 blocks/CU)
};

// ---------------- repack kernel ----------------
template<int D_IN, int D_OUT, int CW4, int D_INP, int WOFF>
__device__ __forceinline__ void repack_layer(const float* __restrict__ W, int idx) {
    constexpr int SZ = 12 * D_INP * CW4;
    if (idx >= SZ) return;
    int j = idx % CW4;
    int r = idx / CW4;
    int k = r % D_INP;
    int q = r / D_INP;          // b*4 + cgrp
    int cgrp = q & 3;
    int b = q >> 2;
    int col = cgrp * CW4 + j;
    float v = 0.f;
    if (col < D_OUT && k < D_IN) v = W[(b * D_IN + k) * D_OUT + col];
    g_packW[WOFF + idx] = v;
}

__global__ void repack_kernel(const float* __restrict__ W0, const float* __restrict__ W1,
                              const float* __restrict__ W2, const float* __restrict__ W3,
                              const float* __restrict__ W4) {
    int idx = blockIdx.x * 256 + threadIdx.x;
    switch (blockIdx.y) {
    case 0: repack_layer<74, 70, 20, 76,     0>(W0, idx); break;
    case 1: repack_layer<70, 65, 20, 72, 18240>(W1, idx); break;
    case 2: repack_layer<65, 60, 16, 68, 35520>(W2, idx); break;
    case 3: repack_layer<60, 55, 16, 60, 48576>(W3, idx); break;
    case 4: repack_layer<55, 37, 12, 56, 60096>(W4, idx); break;
    }
}

// ---------------- propagation (CSR gather) ----------------
// out[n][:] = nrm[n] * sum_{e: dst==n} csr_val[e] * in[src_e][:]
template<int D_IN>
__device__ __forceinline__ void propagate(const float* __restrict__ in,
                                          float* __restrict__ outb,
                                          const unsigned short* __restrict__ csr_src,
                                          const float* __restrict__ csr_val,
                                          const int* __restrict__ row_start,
                                          const float* __restrict__ nrm,
                                          int tid)
{
    constexpr int CH = (D_IN + 3) / 4;            // float4 chunks (pad finite)
    constexpr int R4 = STRIDE / 4;                // 19 float4 per row
    const float4* __restrict__ in4 = (const float4*)in;
    float4* __restrict__ out4 = (float4*)outb;

    for (int t = tid; t < NODES * CH; t += NTHR) {
        int n = t / CH;                           // compile-time divisor
        int c = t - n * CH;
        int beg = row_start[n], end = row_start[n + 1];
        float ax = 0.f, ay = 0.f, az = 0.f, aw = 0.f;
        int e = beg;
        for (; e + 3 < end; e += 4) {
            int   s0 = csr_src[e],     s1 = csr_src[e + 1];
            int   s2 = csr_src[e + 2], s3 = csr_src[e + 3];
            float c0 = csr_val[e],     c1 = csr_val[e + 1];
            float c2 = csr_val[e + 2], c3 = csr_val[e + 3];
            float4 v0 = in4[s0 * R4 + c];
            float4 v1 = in4[s1 * R4 + c];
            float4 v2 = in4[s2 * R4 + c];
            float4 v3 = in4[s3 * R4 + c];
            ax = fmaf(c0, v0.x, ax); ay = fmaf(c0, v0.y, ay);
            az = fmaf(c0, v0.z, az); aw = fmaf(c0, v0.w, aw);
            ax = fmaf(c1, v1.x, ax); ay = fmaf(c1, v1.y, ay);
            az = fmaf(c1, v1.z, az); aw = fmaf(c1, v1.w, aw);
            ax = fmaf(c2, v2.x, ax); ay = fmaf(c2, v2.y, ay);
            az = fmaf(c2, v2.z, az); aw = fmaf(c2, v2.w, aw);
            ax = fmaf(c3, v3.x, ax); ay = fmaf(c3, v3.y, ay);
            az = fmaf(c3, v3.z, az); aw = fmaf(c3, v3.w, aw);
        }
        for (; e < end; ++e) {
            int s = csr_src[e];
            float sc = csr_val[e];
            float4 v = in4[s * R4 + c];
            ax = fmaf(sc, v.x, ax); ay = fmaf(sc, v.y, ay);
            az = fmaf(sc, v.z, az); aw = fmaf(sc, v.w, aw);
        }
        float sn = nrm[n];
        float4 o = { ax * sn, ay * sn, az * sn, aw * sn };
        out4[n * R4 + c] = o;
    }
}

// ---------------- one TAGConv layer ----------------
template<int D_IN, int D_OUT, int CW4, int D_INP, int WOFF>
__device__ __forceinline__ void tag_layer(Smem& sm,
                                          const float* __restrict__ Bv,
                                          int tid)
{
    constexpr int Q   = CW4 / 4;                  // float4 W loads per k row
    constexpr int CHP = D_INP / 4;                // h chunks

    // task t = cgrp*100 + node; tasks 0..399 live in waves 0..6 (wave 6 is
    // 1/4 active via clamp), wave 7 skips dense entirely. cgrp/node/colbase
    // are per-lane; control flow stays wave-uniform (CW4 same for all cgrps).
    const int  tcl     = tid < DENSE_TASKS ? tid : DENSE_TASKS - 1;
    const int  cgrp    = tcl / NODES;
    const int  node    = tcl - cgrp * NODES;
    const int  colbase = cgrp * CW4;
    const bool dense   = tid < DENSE_THR;         // wave-uniform

    float acc[CW4];
#pragma unroll
    for (int j = 0; j < CW4; ++j) acc[j] = 0.f;

    auto gblock = [&](const float* __restrict__ buf, int b) {
        const float4* __restrict__ wb =
            (const float4*)&g_packW[WOFF + (b * 4 + cgrp) * D_INP * CW4];
        const float4* __restrict__ hrow4 = (const float4*)(buf + node * STRIDE);
#pragma unroll 2
        for (int cc = 0; cc < CHP; ++cc) {
            const float4 h4 = hrow4[cc];          // ds_read_b128 (lgkmcnt)
            const float4* __restrict__ wk = wb + cc * 4 * Q;  // vmcnt loads
            const float hv0 = h4.x, hv1 = h4.y, hv2 = h4.z, hv3 = h4.w;
#pragma unroll
            for (int q = 0; q < Q; ++q) {
                float4 w0 = wk[0 * Q + q];
                float4 w1 = wk[1 * Q + q];
                float4 w2 = wk[2 * Q + q];
                float4 w3 = wk[3 * Q + q];
                acc[4*q+0] = fmaf(hv3, w3.x, fmaf(hv2, w2.x, fmaf(hv1, w1.x, fmaf(hv0, w0.x, acc[4*q+0]))));
                acc[4*q+1] = fmaf(hv3, w3.y, fmaf(hv2, w2.y, fmaf(hv1, w1.y, fmaf(hv0, w0.y, acc[4*q+1]))));
                acc[4*q+2] = fmaf(hv3, w3.z, fmaf(hv2, w2.z, fmaf(hv1, w1.z, fmaf(hv0, w0.z, acc[4*q+2]))));
                acc[4*q+3] = fmaf(hv3, w3.w, fmaf(hv2, w2.w, fmaf(hv1, w1.w, fmaf(hv0, w0.w, acc[4*q+3]))));
            }
        }
    };

    // gblock only READS its buffer; propagate READS the same buffer and writes
    // the other one -> a wave may run propagate before/while others gblock.
    // feats block 0: h (bufA); then hop1 bufA->bufB (bufB dead, no race)
    if (dense) gblock(sm.bufA, 0);
    propagate<D_IN>(sm.bufA, sm.bufB, sm.csr_src, sm.csr_val,
                    sm.row_start, sm.nrm, tid);
    __syncthreads();
    // feats block 1: hop1 (bufB); then hop2 bufB->bufA (bufA reads all done)
    if (dense) gblock(sm.bufB, 1);
    propagate<D_IN>(sm.bufB, sm.bufA, sm.csr_src, sm.csr_val,
                    sm.row_start, sm.nrm, tid);
    __syncthreads();
    // feats block 2: hop2 (bufA)
    if (dense) gblock(sm.bufA, 2);
    __syncthreads();    // all reads of bufA complete before h' overwrite

    if (tid < DENSE_TASKS) {
#pragma unroll
        for (int j = 0; j < CW4; ++j) {
            int c = colbase + j;          // per-lane
            if (c < D_OUT)
                sm.bufA[node * STRIDE + c] = fmaxf(acc[j] + Bv[c], 0.f);
        }
    }
    __syncthreads();
}

__global__ __launch_bounds__(NTHR, 4)   // 4 waves/EU -> VGPR<=128, keeps 2 blocks/CU
void drug_graph_conv_kernel(
    const float* __restrict__ x,
    const int*   __restrict__ src,
    const int*   __restrict__ dst,
    const float* __restrict__ b0, const float* __restrict__ b1,
    const float* __restrict__ b2, const float* __restrict__ b3,
    const float* __restrict__ b4,
    const float* __restrict__ gate_w, const float* __restrict__ gate_b,
    float* __restrict__ out)
{
    __shared__ Smem sm;
    const int g     = blockIdx.x;
    const int tid   = threadIdx.x;
    const int nbase = g * NODES;

    // ---- stage x (100 x 74) into bufA at stride 76, dwordx4 loads ----
    // graph slab is 7400 floats, 16B-aligned (g*29,600B). Elements of one
    // float4 may straddle a row boundary -> per-element row/col arithmetic.
    {
        const float4* __restrict__ x4 = (const float4*)(x + (size_t)nbase * 74);
        for (int t = tid; t < NODES * 74 / 4; t += NTHR) {   // 1850
            float4 v = x4[t];
            int idx = 4 * t;
#pragma unroll
            for (int k = 0; k < 4; ++k) {
                int ik = idx + k;
                int n  = ik / 74;               // const-divisor mul-shift
                int d  = ik - n * 74;
                float val = (k == 0) ? v.x : (k == 1) ? v.y : (k == 2) ? v.z : v.w;
                sm.bufA[n * STRIDE + d] = val;
            }
        }
    }
    for (int t = tid; t < NODES * 2; t += NTHR) {
        int n = t >> 1;
        sm.bufA[n * STRIDE + 74 + (t & 1)] = 0.f;
    }

    // ---- degree count ----
    if (tid < NODES) sm.cntg[tid] = 0;
    __syncthreads();
    int es = 0, ed = 0;
    const bool ethr = tid < EDGES;
    if (ethr) {
        es = src[g * EDGES + tid] - nbase;
        ed = dst[g * EDGES + tid] - nbase;
        atomicAdd(&sm.cntg[ed], 1);
    }
    __syncthreads();

    // ---- norm + CSR row offsets (wave-0 shuffle scan over 100 degrees) ----
    if (tid < NODES) sm.nrm[tid] = rsqrtf((float)max(sm.cntg[tid], 1));
    if (tid < 64) {
        int v1 = (tid < NODES) ? sm.cntg[tid] : 0;
        int l2 = tid + 64;
        int v2 = (l2 < NODES) ? sm.cntg[l2] : 0;
        int s1 = v1;
#pragma unroll
        for (int d = 1; d < 64; d <<= 1) {
            int t2 = __shfl_up(s1, d, 64);
            if (tid >= d) s1 += t2;
        }
        int tot1 = __shfl(s1, 63, 64);
        int s2 = v2;
#pragma unroll
        for (int d = 1; d < 64; d <<= 1) {
            int t2 = __shfl_up(s2, d, 64);
            if (tid >= d) s2 += t2;
        }
        s2 += tot1;
        if (tid == 0) sm.row_start[0] = 0;
        sm.row_start[tid + 1] = s1;
        if (l2 < NODES) sm.row_start[l2 + 1] = s2;
    }
    __syncthreads();
    if (tid < NODES) sm.cntg[tid] = 0;   // reuse as CSR fill cursor
    __syncthreads();
    if (ethr) {
        int pos = atomicAdd(&sm.cntg[ed], 1);
        int slot = sm.row_start[ed] + pos;
        sm.csr_src[slot] = (unsigned short)es;
        sm.csr_val[slot] = sm.nrm[es];
    }
    __syncthreads();

    // ---- 5 TAGConv layers ----
    tag_layer<74, 70, 20, 76,     0>(sm, b0, tid);
    tag_layer<70, 65, 20, 72, 18240>(sm, b1, tid);
    tag_layer<65, 60, 16, 68, 35520>(sm, b2, tid);
    tag_layer<60, 55, 16, 60, 48576>(sm, b3, tid);
    tag_layer<55, 37, 12, 56, 60096>(sm, b4, tid);
    // bufA: final h, 100 x 37, stride 76

    // ---- gate + softmax + pool (gate stored in cntg as float) ----
    float* gate = (float*)sm.cntg;
    if (tid < NODES) {
        float s = gate_b[0];
#pragma unroll
        for (int k = 0; k < 37; ++k)
            s = fmaf(sm.bufA[tid * STRIDE + k], gate_w[k], s);
        gate[tid] = s;
    }
    __syncthreads();
    if (tid < 64) {
        float v1 = (tid < NODES) ? gate[tid] : -INFINITY;
        float v2 = (tid + 64 < NODES) ? gate[tid + 64] : -INFINITY;
        float m = fmaxf(v1, v2);
#pragma unroll
        for (int d = 32; d; d >>= 1) m = fmaxf(m, __shfl_xor(m, d, 64));
        float e1 = (tid < NODES) ? __expf(v1 - m) : 0.f;
        float e2 = (tid + 64 < NODES) ? __expf(v2 - m) : 0.f;
        float z = e1 + e2;
#pragma unroll
        for (int d = 32; d; d >>= 1) z += __shfl_xor(z, d, 64);
        float inv = 1.f / z;
        if (tid < NODES) gate[tid] = e1 * inv;
        if (tid + 64 < NODES) gate[tid + 64] = e2 * inv;
    }
    __syncthreads();
    if (tid < 37) {
        float p = 0.f;
        for (int n = 0; n < NODES; ++n)
            p = fmaf(gate[n], sm.bufA[n * STRIDE + tid], p);
        out[g * 37 + tid] = p;
    }
}

extern "C" void kernel_launch(void* const* d_in, const int* in_sizes, int n_in,
                              void* d_out, int out_size, void* d_ws, size_t ws_size,
                              hipStream_t stream) {
    const float* x   = (const float*)d_in[0];
    const int*   src = (const int*)  d_in[1];
    const int*   dst = (const int*)  d_in[2];
    // d_in[3] = graph_ids (implicit: node / 100) -- unused
    const float* W0 = (const float*)d_in[4];  const float* b0 = (const float*)d_in[5];
    const float* W1 = (const float*)d_in[6];  const float* b1 = (const float*)d_in[7];
    const float* W2 = (const float*)d_in[8];  const float* b2 = (const float*)d_in[9];
    const float* W3 = (const float*)d_in[10]; const float* b3 = (const float*)d_in[11];
    const float* W4 = (const float*)d_in[12]; const float* b4 = (const float*)d_in[13];
    const float* gw = (const float*)d_in[14]; const float* gb = (const float*)d_in[15];
    float* out = (float*)d_out;

    // repack W (max layer 18,240 elems -> 72 blocks of 256, y = layer)
    dim3 rg(72, 5, 1);
    repack_kernel<<<rg, 256, 0, stream>>>(W0, W1, W2, W3, W4);

    drug_graph_conv_kernel<<<5000, NTHR, 0, stream>>>(
        x, src, dst, b0, b1, b2, b3, b4, gw, gb, out);
}

// Round 2
// 1321.080 us; speedup vs baseline: 3.2860x; 3.2860x over previous
//
#include <hip/hip_runtime.h>
#include <math.h>

// DrugGraphConv: 5000 graphs x 100 nodes x 400 edges, 5 TAGConv(K=2) layers
// DIMS = [74,70,65,60,55,37], gated softmax pooling per graph.
//
// R6 (1.33ms): wave-uniform cgrp (readfirstlane) -> scalar/broadcast W path,
// VGPR 52, VALUBusy 66%, Occ 44% (LDS 64,404B -> 2 blocks/CU). VALU-issue +
// latency bound; HBM 0.8%, bank conflicts ~3.5% of cycles.
// R7 (4.34ms, REVERTED): per-lane cgrp broke W-address uniformity -> per-lane
// vector W loads at VGPR 64 -> latency-serialized inner loop, VALUBusy 19%.
// Lesson: W addresses MUST stay wave-uniform.
//
// R8: exact R6 structure; single change in gblock: hoist all 4*Q W float4
// loads of the chunk into a statically-indexed wreg[] before the FMAs
// (one latency drain per chunk instead of one per 4-5 loads). VGPR est ~119;
// __launch_bounds__(512,4) caps at 128 so 2-block co-residency is preserved.

constexpr int NODES  = 100;
constexpr int EDGES  = 400;
constexpr int STRIDE = 76;     // mult of 4: b128 rows 2-way-bank-free
constexpr int NTHR   = 512;

// packed W: per layer, per (b,cgrp): D_INP rows x CW4 cols, zero-padded.
// sizes: 12*76*20 + 12*72*20 + 12*68*16 + 12*60*16 + 12*56*12 = 68,160 floats
__device__ __align__(16) float g_packW[68160];

struct __align__(16) Smem {
    float bufA[NODES * STRIDE];        // 30,400 B
    float bufB[NODES * STRIDE];        // 30,400 B
    float csr_val[EDGES];              //  1,600 B (nrm[src] per CSR slot)
    unsigned short csr_src[EDGES];     //    800 B (src node ids < 100)
    int   row_start[NODES + 1];        //    404 B
    int   cntg[NODES];                 //    400 B (cnt during setup, gate after)
    float nrm[NODES];                  //    400 B  => 64,404 B (2 blocks/CU)
};

// ---------------- repack kernel ----------------
template<int D_IN, int D_OUT, int CW4, int D_INP, int WOFF>
__device__ __forceinline__ void repack_layer(const float* __restrict__ W, int idx) {
    constexpr int SZ = 12 * D_INP * CW4;
    if (idx >= SZ) return;
    int j = idx % CW4;
    int r = idx / CW4;
    int k = r % D_INP;
    int q = r / D_INP;          // b*4 + cgrp
    int cgrp = q & 3;
    int b = q >> 2;
    int col = cgrp * CW4 + j;
    float v = 0.f;
    if (col < D_OUT && k < D_IN) v = W[(b * D_IN + k) * D_OUT + col];
    g_packW[WOFF + idx] = v;
}

__global__ void repack_kernel(const float* __restrict__ W0, const float* __restrict__ W1,
                              const float* __restrict__ W2, const float* __restrict__ W3,
                              const float* __restrict__ W4) {
    int idx = blockIdx.x * 256 + threadIdx.x;
    switch (blockIdx.y) {
    case 0: repack_layer<74, 70, 20, 76,     0>(W0, idx); break;
    case 1: repack_layer<70, 65, 20, 72, 18240>(W1, idx); break;
    case 2: repack_layer<65, 60, 16, 68, 35520>(W2, idx); break;
    case 3: repack_layer<60, 55, 16, 60, 48576>(W3, idx); break;
    case 4: repack_layer<55, 37, 12, 56, 60096>(W4, idx); break;
    }
}

// ---------------- propagation (CSR gather) ----------------
// out[n][:] = nrm[n] * sum_{e: dst==n} csr_val[e] * in[src_e][:]
template<int D_IN>
__device__ __forceinline__ void propagate(const float* __restrict__ in,
                                          float* __restrict__ outb,
                                          const unsigned short* __restrict__ csr_src,
                                          const float* __restrict__ csr_val,
                                          const int* __restrict__ row_start,
                                          const float* __restrict__ nrm,
                                          int tid)
{
    constexpr int CH = (D_IN + 3) / 4;            // float4 chunks (pad finite)
    constexpr int R4 = STRIDE / 4;                // 19 float4 per row
    const float4* __restrict__ in4 = (const float4*)in;
    float4* __restrict__ out4 = (float4*)outb;

    for (int t = tid; t < NODES * CH; t += NTHR) {
        int n = t / CH;                           // compile-time divisor
        int c = t - n * CH;
        int beg = row_start[n], end = row_start[n + 1];
        float ax = 0.f, ay = 0.f, az = 0.f, aw = 0.f;
        int e = beg;
        for (; e + 3 < end; e += 4) {
            int   s0 = csr_src[e],     s1 = csr_src[e + 1];
            int   s2 = csr_src[e + 2], s3 = csr_src[e + 3];
            float c0 = csr_val[e],     c1 = csr_val[e + 1];
            float c2 = csr_val[e + 2], c3 = csr_val[e + 3];
            float4 v0 = in4[s0 * R4 + c];
            float4 v1 = in4[s1 * R4 + c];
            float4 v2 = in4[s2 * R4 + c];
            float4 v3 = in4[s3 * R4 + c];
            ax = fmaf(c0, v0.x, ax); ay = fmaf(c0, v0.y, ay);
            az = fmaf(c0, v0.z, az); aw = fmaf(c0, v0.w, aw);
            ax = fmaf(c1, v1.x, ax); ay = fmaf(c1, v1.y, ay);
            az = fmaf(c1, v1.z, az); aw = fmaf(c1, v1.w, aw);
            ax = fmaf(c2, v2.x, ax); ay = fmaf(c2, v2.y, ay);
            az = fmaf(c2, v2.z, az); aw = fmaf(c2, v2.w, aw);
            ax = fmaf(c3, v3.x, ax); ay = fmaf(c3, v3.y, ay);
            az = fmaf(c3, v3.z, az); aw = fmaf(c3, v3.w, aw);
        }
        for (; e < end; ++e) {
            int s = csr_src[e];
            float sc = csr_val[e];
            float4 v = in4[s * R4 + c];
            ax = fmaf(sc, v.x, ax); ay = fmaf(sc, v.y, ay);
            az = fmaf(sc, v.z, az); aw = fmaf(sc, v.w, aw);
        }
        float sn = nrm[n];
        float4 o = { ax * sn, ay * sn, az * sn, aw * sn };
        out4[n * R4 + c] = o;
    }
}

// ---------------- one TAGConv layer ----------------
template<int D_IN, int D_OUT, int CW4, int D_INP, int WOFF>
__device__ __forceinline__ void tag_layer(Smem& sm,
                                          const float* __restrict__ Bv,
                                          int tid)
{
    constexpr int Q   = CW4 / 4;                  // float4 W loads per k row
    constexpr int CHP = D_INP / 4;                // h chunks

    const int wave    = __builtin_amdgcn_readfirstlane(tid >> 6); // uniform
    const int lane    = tid & 63;
    const int cgrp    = wave >> 1;                // 0..3 uniform
    const int nhalf   = wave & 1;                 // 0..1 uniform
    const int node    = nhalf * 64 + lane;
    const int nclamp  = node > NODES - 1 ? NODES - 1 : node;
    const int colbase = cgrp * CW4;               // uniform

    float acc[CW4];
#pragma unroll
    for (int j = 0; j < CW4; ++j) acc[j] = 0.f;

    auto gblock = [&](const float* __restrict__ buf, int b) {
        const float4* __restrict__ wb =
            (const float4*)&g_packW[WOFF + (b * 4 + cgrp) * D_INP * CW4];
        const float4* __restrict__ hrow4 = (const float4*)(buf + nclamp * STRIDE);
#pragma unroll 1
        for (int cc = 0; cc < CHP; ++cc) {
            const float4 h4 = hrow4[cc];          // ds_read_b128 (lgkmcnt)
            const float4* __restrict__ wk = wb + cc * 4 * Q;
            // hoist ALL 4*Q W loads of this chunk before any FMA: one
            // latency drain per chunk. Static indices -> registers.
            float4 wreg[4 * Q];
#pragma unroll
            for (int i = 0; i < 4 * Q; ++i) wreg[i] = wk[i];
            const float hv0 = h4.x, hv1 = h4.y, hv2 = h4.z, hv3 = h4.w;
#pragma unroll
            for (int q = 0; q < Q; ++q) {
                float4 w0 = wreg[0 * Q + q];
                float4 w1 = wreg[1 * Q + q];
                float4 w2 = wreg[2 * Q + q];
                float4 w3 = wreg[3 * Q + q];
                acc[4*q+0] = fmaf(hv3, w3.x, fmaf(hv2, w2.x, fmaf(hv1, w1.x, fmaf(hv0, w0.x, acc[4*q+0]))));
                acc[4*q+1] = fmaf(hv3, w3.y, fmaf(hv2, w2.y, fmaf(hv1, w1.y, fmaf(hv0, w0.y, acc[4*q+1]))));
                acc[4*q+2] = fmaf(hv3, w3.z, fmaf(hv2, w2.z, fmaf(hv1, w1.z, fmaf(hv0, w0.z, acc[4*q+2]))));
                acc[4*q+3] = fmaf(hv3, w3.w, fmaf(hv2, w2.w, fmaf(hv1, w1.w, fmaf(hv0, w0.w, acc[4*q+3]))));
            }
        }
    };

    // feats block 0: h (bufA); then hop1 bufA->bufB (bufB dead, no race)
    gblock(sm.bufA, 0);
    propagate<D_IN>(sm.bufA, sm.bufB, sm.csr_src, sm.csr_val,
                    sm.row_start, sm.nrm, tid);
    __syncthreads();
    // feats block 1: hop1 (bufB); then hop2 bufB->bufA (bufA reads all done)
    gblock(sm.bufB, 1);
    propagate<D_IN>(sm.bufB, sm.bufA, sm.csr_src, sm.csr_val,
                    sm.row_start, sm.nrm, tid);
    __syncthreads();
    // feats block 2: hop2 (bufA)
    gblock(sm.bufA, 2);
    __syncthreads();    // all reads of bufA complete before h' overwrite

    if (node < NODES) {
#pragma unroll
        for (int j = 0; j < CW4; ++j) {
            int c = colbase + j;          // uniform per j
            if (c < D_OUT)
                sm.bufA[node * STRIDE + c] = fmaxf(acc[j] + Bv[c], 0.f);
        }
    }
    __syncthreads();
}

__global__ __launch_bounds__(NTHR, 4)  // cap VGPR at 128: keep 2 blocks/CU
void drug_graph_conv_kernel(
    const float* __restrict__ x,
    const int*   __restrict__ src,
    const int*   __restrict__ dst,
    const float* __restrict__ b0, const float* __restrict__ b1,
    const float* __restrict__ b2, const float* __restrict__ b3,
    const float* __restrict__ b4,
    const float* __restrict__ gate_w, const float* __restrict__ gate_b,
    float* __restrict__ out)
{
    __shared__ Smem sm;
    const int g     = blockIdx.x;
    const int tid   = threadIdx.x;
    const int nbase = g * NODES;

    // ---- stage x (100 x 74) into bufA at stride 76; zero pad cols 74,75 ----
    for (int t = tid; t < NODES * 74; t += NTHR) {
        int n = t / 74;
        int d = t - n * 74;
        sm.bufA[n * STRIDE + d] = x[nbase * 74 + t];
    }
    for (int t = tid; t < NODES * 2; t += NTHR) {
        int n = t >> 1;
        sm.bufA[n * STRIDE + 74 + (t & 1)] = 0.f;
    }

    // ---- degree count ----
    if (tid < NODES) sm.cntg[tid] = 0;
    __syncthreads();
    int es = 0, ed = 0;
    const bool ethr = tid < EDGES;
    if (ethr) {
        es = src[g * EDGES + tid] - nbase;
        ed = dst[g * EDGES + tid] - nbase;
        atomicAdd(&sm.cntg[ed], 1);
    }
    __syncthreads();

    // ---- norm + CSR row offsets (wave-0 shuffle scan over 100 degrees) ----
    if (tid < NODES) sm.nrm[tid] = rsqrtf((float)max(sm.cntg[tid], 1));
    if (tid < 64) {
        int v1 = (tid < NODES) ? sm.cntg[tid] : 0;
        int l2 = tid + 64;
        int v2 = (l2 < NODES) ? sm.cntg[l2] : 0;
        int s1 = v1;
#pragma unroll
        for (int d = 1; d < 64; d <<= 1) {
            int t2 = __shfl_up(s1, d, 64);
            if (tid >= d) s1 += t2;
        }
        int tot1 = __shfl(s1, 63, 64);
        int s2 = v2;
#pragma unroll
        for (int d = 1; d < 64; d <<= 1) {
            int t2 = __shfl_up(s2, d, 64);
            if (tid >= d) s2 += t2;
        }
        s2 += tot1;
        if (tid == 0) sm.row_start[0] = 0;
        sm.row_start[tid + 1] = s1;
        if (l2 < NODES) sm.row_start[l2 + 1] = s2;
    }
    __syncthreads();
    if (tid < NODES) sm.cntg[tid] = 0;   // reuse as CSR fill cursor
    __syncthreads();
    if (ethr) {
        int pos = atomicAdd(&sm.cntg[ed], 1);
        int slot = sm.row_start[ed] + pos;
        sm.csr_src[slot] = (unsigned short)es;
        sm.csr_val[slot] = sm.nrm[es];
    }
    __syncthreads();

    // ---- 5 TAGConv layers ----
    tag_layer<74, 70, 20, 76,     0>(sm, b0, tid);
    tag_layer<70, 65, 20, 72, 18240>(sm, b1, tid);
    tag_layer<65, 60, 16, 68, 35520>(sm, b2, tid);
    tag_layer<60, 55, 16, 60, 48576>(sm, b3, tid);
    tag_layer<55, 37, 12, 56, 60096>(sm, b4, tid);
    // bufA: final h, 100 x 37, stride 76

    // ---- gate + softmax + pool (gate stored in cntg as float) ----
    float* gate = (float*)sm.cntg;
    if (tid < NODES) {
        float s = gate_b[0];
#pragma unroll
        for (int k = 0; k < 37; ++k)
            s = fmaf(sm.bufA[tid * STRIDE + k], gate_w[k], s);
        gate[tid] = s;
    }
    __syncthreads();
    if (tid < 64) {
        float v1 = (tid < NODES) ? gate[tid] : -INFINITY;
        float v2 = (tid + 64 < NODES) ? gate[tid + 64] : -INFINITY;
        float m = fmaxf(v1, v2);
#pragma unroll
        for (int d = 32; d; d >>= 1) m = fmaxf(m, __shfl_xor(m, d, 64));
        float e1 = (tid < NODES) ? __expf(v1 - m) : 0.f;
        float e2 = (tid + 64 < NODES) ? __expf(v2 - m) : 0.f;
        float z = e1 + e2;
#pragma unroll
        for (int d = 32; d; d >>= 1) z += __shfl_xor(z, d, 64);
        float inv = 1.f / z;
        if (tid < NODES) gate[tid] = e1 * inv;
        if (tid + 64 < NODES) gate[tid + 64] = e2 * inv;
    }
    __syncthreads();
    if (tid < 37) {
        float p = 0.f;
        for (int n = 0; n < NODES; ++n)
            p = fmaf(gate[n], sm.bufA[n * STRIDE + tid], p);
        out[g * 37 + tid] = p;
    }
}

extern "C" void kernel_launch(void* const* d_in, const int* in_sizes, int n_in,
                              void* d_out, int out_size, void* d_ws, size_t ws_size,
                              hipStream_t stream) {
    const float* x   = (const float*)d_in[0];
    const int*   src = (const int*)  d_in[1];
    const int*   dst = (const int*)  d_in[2];
    // d_in[3] = graph_ids (implicit: node / 100) -- unused
    const float* W0 = (const float*)d_in[4];  const float* b0 = (const float*)d_in[5];
    const float* W1 = (const float*)d_in[6];  const float* b1 = (const float*)d_in[7];
    const float* W2 = (const float*)d_in[8];  const float* b2 = (const float*)d_in[9];
    const float* W3 = (const float*)d_in[10]; const float* b3 = (const float*)d_in[11];
    const float* W4 = (const float*)d_in[12]; const float* b4 = (const float*)d_in[13];
    const float* gw = (const float*)d_in[14]; const float* gb = (const float*)d_in[15];
    float* out = (float*)d_out;

    // repack W (max layer 18,240 elems -> 72 blocks of 256, y = layer)
    dim3 rg(72, 5, 1);
    repack_kernel<<<rg, 256, 0, stream>>>(W0, W1, W2, W3, W4);

    drug_graph_conv_kernel<<<5000, NTHR, 0, stream>>>(
        x, src, dst, b0, b1, b2, b3, b4, gw, gb, out);
}

// Round 3
// 846.133 us; speedup vs baseline: 5.1305x; 1.5613x over previous
//
#include <hip/hip_runtime.h>
#include <math.h>

// DrugGraphConv: 5000 graphs x 100 nodes x 400 edges, 5 TAGConv(K=2) layers
// DIMS = [74,70,65,60,55,37], gated softmax pooling per graph.
//
// R6/R8 (1.32ms): fp32-VALU dense, VGPR 52, VALUBusy 67%, MfmaUtil 0,
// Occ 44% (LDS 64,404B -> 2 blocks/CU). Dense FMA issue floor ~1.33M cy/CU
// (42% of runtime) IS the bottleneck -- scheduling tricks are null (R8).
// R7 (4.3ms): per-lane W addrs broke uniformity -- reverted.
//
// R9: dense matmul on MFMA bf16 hi/lo split: D ~= AhBh + AhBl + AlBh
// (3x mfma_f32_16x16x32_bf16, fp32 acc; ~2e-5 rel err from dropped AlBl).
// A-frags: split in-register from fp32 LDS rows (truncation split, ~36 VALU
// per k-tile). B-frags: pre-split+frag-packed by repack kernel (32B/lane
// records, L2-resident). k-map consistency between A and B is by
// construction (same (g,i)->k formula both sides) so the assumed operand
// layout cancels even if wrong; only the verified C/D layout matters
// (col=lane&15, row=(lane>>4)*4+reg). LDS k-reads clamped to col<=75 so
// pad lanes read finite data (W rows k>=D_IN are zeroed -> products 0).
// Waves 0..6 = m-tiles (16 rows each), wave 7 skips dense. Pool epilogue
// parallelized across all 8 waves. LDS/occupancy unchanged.

typedef __attribute__((ext_vector_type(8))) short bf16x8;
typedef __attribute__((ext_vector_type(4))) float f32x4;

constexpr int NODES  = 100;
constexpr int EDGES  = 400;
constexpr int STRIDE = 76;     // floats per LDS row (mult of 4)
constexpr int NTHR   = 512;

// packed W frags: per layer, per (b,kt,nt): 64 lanes x (8 bf16 hi + 8 bf16 lo)
// = 2048B per frag-tile. tiles: L0 3*3*5=45, L1 45, L2 36, L3 24, L4 18.
// u32 offsets: 0, 23040, 46080, 64512, 76800; total 86016 u32 = 344KB.
__device__ __align__(16) unsigned g_packW[86016];

struct __align__(16) Smem {
    float bufA[NODES * STRIDE];        // 30,400 B
    float bufB[NODES * STRIDE];        // 30,400 B
    float csr_val[EDGES];              //  1,600 B (nrm[src]; pool scratch later)
    unsigned short csr_src[EDGES];     //    800 B
    int   row_start[NODES + 1];        //    404 B
    int   cntg[NODES];                 //    400 B (cnt setup, gate after)
    float nrm[NODES];                  //    400 B  => 64,404 B (2 blocks/CU)
};

union FragU { unsigned u[4]; uint4 q; bf16x8 s; };

// truncation hi/lo bf16 split of a pair, packed little-endian (a -> low16).
__device__ __forceinline__ void split_pair(float a, float b,
                                           unsigned& h, unsigned& l) {
    unsigned ua = __float_as_uint(a), ub = __float_as_uint(b);
    unsigned ha = ua & 0xFFFF0000u,  hb = ub & 0xFFFF0000u;
    h = (ua >> 16) | hb;
    float ra = a - __uint_as_float(ha);
    float rb = b - __uint_as_float(hb);
    l = (__float_as_uint(ra) >> 16) | (__float_as_uint(rb) & 0xFFFF0000u);
}

// ---------------- repack kernel: W -> frag-ready bf16 hi/lo ----------------
template<int D_IN, int D_OUT, int KT, int NT, int WOFF_U32>
__device__ __forceinline__ void repack_layer(const float* __restrict__ W, int idx) {
    constexpr int TILES = 3 * KT * NT;
    if (idx >= TILES * 64) return;
    int lane = idx & 63, tile = idx >> 6;
    int nt = tile % NT;
    int kt = (tile / NT) % KT;
    int b  = tile / (NT * KT);
    int col = nt * 16 + (lane & 15);
    int kg  = (lane >> 4) << 2;
    float v[8];
#pragma unroll
    for (int i = 0; i < 8; ++i) {
        int k = kt * 32 + ((i >= 4) ? 16 : 0) + kg + (i & 3);
        float f = 0.f;
        if (k < D_IN && col < D_OUT) f = W[(b * D_IN + k) * D_OUT + col];
        v[i] = f;
    }
    unsigned hu[4], lu[4];
#pragma unroll
    for (int p = 0; p < 4; ++p) split_pair(v[2*p], v[2*p+1], hu[p], lu[p]);
    unsigned* dst = g_packW + WOFF_U32 + (tile * 64 + lane) * 8;
    *(uint4*)(dst)     = make_uint4(hu[0], hu[1], hu[2], hu[3]);
    *(uint4*)(dst + 4) = make_uint4(lu[0], lu[1], lu[2], lu[3]);
}

__global__ void repack_kernel(const float* __restrict__ W0, const float* __restrict__ W1,
                              const float* __restrict__ W2, const float* __restrict__ W3,
                              const float* __restrict__ W4) {
    int idx = blockIdx.x * 256 + threadIdx.x;
    switch (blockIdx.y) {
    case 0: repack_layer<74, 70, 3, 5,     0>(W0, idx); break;
    case 1: repack_layer<70, 65, 3, 5, 23040>(W1, idx); break;
    case 2: repack_layer<65, 60, 3, 4, 46080>(W2, idx); break;
    case 3: repack_layer<60, 55, 2, 4, 64512>(W3, idx); break;
    case 4: repack_layer<55, 37, 2, 3, 76800>(W4, idx); break;
    }
}

// ---------------- propagation (CSR gather, fp32 VALU -- unchanged) ---------
template<int D_IN>
__device__ __forceinline__ void propagate(const float* __restrict__ in,
                                          float* __restrict__ outb,
                                          const unsigned short* __restrict__ csr_src,
                                          const float* __restrict__ csr_val,
                                          const int* __restrict__ row_start,
                                          const float* __restrict__ nrm,
                                          int tid)
{
    constexpr int CH = (D_IN + 3) / 4;
    constexpr int R4 = STRIDE / 4;
    const float4* __restrict__ in4 = (const float4*)in;
    float4* __restrict__ out4 = (float4*)outb;

    for (int t = tid; t < NODES * CH; t += NTHR) {
        int n = t / CH;
        int c = t - n * CH;
        int beg = row_start[n], end = row_start[n + 1];
        float ax = 0.f, ay = 0.f, az = 0.f, aw = 0.f;
        int e = beg;
        for (; e + 3 < end; e += 4) {
            int   s0 = csr_src[e],     s1 = csr_src[e + 1];
            int   s2 = csr_src[e + 2], s3 = csr_src[e + 3];
            float c0 = csr_val[e],     c1 = csr_val[e + 1];
            float c2 = csr_val[e + 2], c3 = csr_val[e + 3];
            float4 v0 = in4[s0 * R4 + c];
            float4 v1 = in4[s1 * R4 + c];
            float4 v2 = in4[s2 * R4 + c];
            float4 v3 = in4[s3 * R4 + c];
            ax = fmaf(c0, v0.x, ax); ay = fmaf(c0, v0.y, ay);
            az = fmaf(c0, v0.z, az); aw = fmaf(c0, v0.w, aw);
            ax = fmaf(c1, v1.x, ax); ay = fmaf(c1, v1.y, ay);
            az = fmaf(c1, v1.z, az); aw = fmaf(c1, v1.w, aw);
            ax = fmaf(c2, v2.x, ax); ay = fmaf(c2, v2.y, ay);
            az = fmaf(c2, v2.z, az); aw = fmaf(c2, v2.w, aw);
            ax = fmaf(c3, v3.x, ax); ay = fmaf(c3, v3.y, ay);
            az = fmaf(c3, v3.z, az); aw = fmaf(c3, v3.w, aw);
        }
        for (; e < end; ++e) {
            int s = csr_src[e];
            float sc = csr_val[e];
            float4 v = in4[s * R4 + c];
            ax = fmaf(sc, v.x, ax); ay = fmaf(sc, v.y, ay);
            az = fmaf(sc, v.z, az); aw = fmaf(sc, v.w, aw);
        }
        float sn = nrm[n];
        float4 o = { ax * sn, ay * sn, az * sn, aw * sn };
        out4[n * R4 + c] = o;
    }
}

// ---------------- one feats-block of the dense matmul on MFMA --------------
template<int D_IN, int D_OUT, int KT, int NT, int WOFF_U32>
__device__ __forceinline__ void dense_block(const float* __restrict__ buf, int b,
                                            int mt, int lane, f32x4 (&acc)[NT]) {
    int row = mt * 16 + (lane & 15);
    row = row > NODES - 1 ? NODES - 1 : row;   // clamped rows masked at store
    const float* __restrict__ hrow = buf + row * STRIDE;
    const int kg = (lane >> 4) << 2;
    const uint4* __restrict__ wb =
        (const uint4*)(g_packW + WOFF_U32) + b * (KT * NT * 128) + lane * 2;
#pragma unroll 1
    for (int kt = 0; kt < KT; ++kt) {
        // clamp so reads stay inside the row's 76 valid floats (finite data;
        // k>=D_IN lanes are killed by zeroed W rows, value irrelevant).
        int o0 = kt * 32 + kg;      if (o0 > 72) o0 = 72;
        int o1 = kt * 32 + 16 + kg; if (o1 > 72) o1 = 72;
        const float4 f0 = *(const float4*)(hrow + o0);   // ds_read_b128
        const float4 f1 = *(const float4*)(hrow + o1);
        FragU Ah, Al;
        split_pair(f0.x, f0.y, Ah.u[0], Al.u[0]);
        split_pair(f0.z, f0.w, Ah.u[1], Al.u[1]);
        split_pair(f1.x, f1.y, Ah.u[2], Al.u[2]);
        split_pair(f1.z, f1.w, Ah.u[3], Al.u[3]);
#pragma unroll
        for (int nt = 0; nt < NT; ++nt) {
            const uint4* __restrict__ wl = wb + (kt * NT + nt) * 128;
            FragU Bh, Bl;
            Bh.q = wl[0];            // global_load_dwordx4, L2-resident
            Bl.q = wl[1];
            acc[nt] = __builtin_amdgcn_mfma_f32_16x16x32_bf16(Ah.s, Bh.s, acc[nt], 0, 0, 0);
            acc[nt] = __builtin_amdgcn_mfma_f32_16x16x32_bf16(Ah.s, Bl.s, acc[nt], 0, 0, 0);
            acc[nt] = __builtin_amdgcn_mfma_f32_16x16x32_bf16(Al.s, Bh.s, acc[nt], 0, 0, 0);
        }
    }
}

// ---------------- one TAGConv layer ----------------
template<int D_IN, int D_OUT, int KT, int NT, int WOFF_U32>
__device__ __forceinline__ void tag_layer(Smem& sm,
                                          const float* __restrict__ Bv,
                                          int tid)
{
    const int wave  = __builtin_amdgcn_readfirstlane(tid >> 6); // uniform
    const int lane  = tid & 63;
    const bool m_act = wave < 7;      // 7 m-tiles cover 100 rows; wave7 idle

    f32x4 acc[NT];
#pragma unroll
    for (int nt = 0; nt < NT; ++nt) acc[nt] = (f32x4)(0.f);

    // dense reads bufX (cols <=75 only); propagate reads same buf, writes the
    // other -> same no-race argument as R6.
    if (m_act) dense_block<D_IN, D_OUT, KT, NT, WOFF_U32>(sm.bufA, 0, wave, lane, acc);
    propagate<D_IN>(sm.bufA, sm.bufB, sm.csr_src, sm.csr_val,
                    sm.row_start, sm.nrm, tid);
    __syncthreads();
    if (m_act) dense_block<D_IN, D_OUT, KT, NT, WOFF_U32>(sm.bufB, 1, wave, lane, acc);
    propagate<D_IN>(sm.bufB, sm.bufA, sm.csr_src, sm.csr_val,
                    sm.row_start, sm.nrm, tid);
    __syncthreads();
    if (m_act) dense_block<D_IN, D_OUT, KT, NT, WOFF_U32>(sm.bufA, 2, wave, lane, acc);
    __syncthreads();    // all reads of bufA complete before h' overwrite

    if (m_act) {
        // C/D layout (verified): col = lane&15, row_in_tile = (lane>>4)*4 + r
#pragma unroll
        for (int nt = 0; nt < NT; ++nt) {
            int col = nt * 16 + (lane & 15);
            if (col < D_OUT) {
                float bias = Bv[col];
#pragma unroll
                for (int r = 0; r < 4; ++r) {
                    int row = wave * 16 + ((lane >> 4) << 2) + r;
                    if (row < NODES)
                        sm.bufA[row * STRIDE + col] = fmaxf(acc[nt][r] + bias, 0.f);
                }
            }
        }
    }
    __syncthreads();
}

__global__ __launch_bounds__(NTHR, 4)  // VGPR<=128: keep 2 blocks/CU resident
void drug_graph_conv_kernel(
    const float* __restrict__ x,
    const int*   __restrict__ src,
    const int*   __restrict__ dst,
    const float* __restrict__ b0, const float* __restrict__ b1,
    const float* __restrict__ b2, const float* __restrict__ b3,
    const float* __restrict__ b4,
    const float* __restrict__ gate_w, const float* __restrict__ gate_b,
    float* __restrict__ out)
{
    __shared__ Smem sm;
    const int g     = blockIdx.x;
    const int tid   = threadIdx.x;
    const int nbase = g * NODES;

    // ---- stage x (100 x 74) into bufA at stride 76; zero pad cols 74,75 ----
    for (int t = tid; t < NODES * 74; t += NTHR) {
        int n = t / 74;
        int d = t - n * 74;
        sm.bufA[n * STRIDE + d] = x[nbase * 74 + t];
    }
    for (int t = tid; t < NODES * 2; t += NTHR) {
        int n = t >> 1;
        sm.bufA[n * STRIDE + 74 + (t & 1)] = 0.f;
    }

    // ---- degree count ----
    if (tid < NODES) sm.cntg[tid] = 0;
    __syncthreads();
    int es = 0, ed = 0;
    const bool ethr = tid < EDGES;
    if (ethr) {
        es = src[g * EDGES + tid] - nbase;
        ed = dst[g * EDGES + tid] - nbase;
        atomicAdd(&sm.cntg[ed], 1);
    }
    __syncthreads();

    // ---- norm + CSR row offsets (wave-0 shuffle scan over 100 degrees) ----
    if (tid < NODES) sm.nrm[tid] = rsqrtf((float)max(sm.cntg[tid], 1));
    if (tid < 64) {
        int v1 = (tid < NODES) ? sm.cntg[tid] : 0;
        int l2 = tid + 64;
        int v2 = (l2 < NODES) ? sm.cntg[l2] : 0;
        int s1 = v1;
#pragma unroll
        for (int d = 1; d < 64; d <<= 1) {
            int t2 = __shfl_up(s1, d, 64);
            if (tid >= d) s1 += t2;
        }
        int tot1 = __shfl(s1, 63, 64);
        int s2 = v2;
#pragma unroll
        for (int d = 1; d < 64; d <<= 1) {
            int t2 = __shfl_up(s2, d, 64);
            if (tid >= d) s2 += t2;
        }
        s2 += tot1;
        if (tid == 0) sm.row_start[0] = 0;
        sm.row_start[tid + 1] = s1;
        if (l2 < NODES) sm.row_start[l2 + 1] = s2;
    }
    __syncthreads();
    if (tid < NODES) sm.cntg[tid] = 0;   // reuse as CSR fill cursor
    __syncthreads();
    if (ethr) {
        int pos = atomicAdd(&sm.cntg[ed], 1);
        int slot = sm.row_start[ed] + pos;
        sm.csr_src[slot] = (unsigned short)es;
        sm.csr_val[slot] = sm.nrm[es];
    }
    __syncthreads();

    // ---- 5 TAGConv layers (MFMA dense) ----
    tag_layer<74, 70, 3, 5,     0>(sm, b0, tid);
    tag_layer<70, 65, 3, 5, 23040>(sm, b1, tid);
    tag_layer<65, 60, 3, 4, 46080>(sm, b2, tid);
    tag_layer<60, 55, 2, 4, 64512>(sm, b3, tid);
    tag_layer<55, 37, 2, 3, 76800>(sm, b4, tid);
    // bufA: final h, 100 x 37, stride 76

    // ---- gate + softmax + pool (gate stored in cntg as float) ----
    float* gate = (float*)sm.cntg;
    if (tid < NODES) {
        float s = gate_b[0];
#pragma unroll
        for (int k = 0; k < 37; ++k)
            s = fmaf(sm.bufA[tid * STRIDE + k], gate_w[k], s);
        gate[tid] = s;
    }
    __syncthreads();
    if (tid < 64) {
        float v1 = (tid < NODES) ? gate[tid] : -INFINITY;
        float v2 = (tid + 64 < NODES) ? gate[tid + 64] : -INFINITY;
        float m = fmaxf(v1, v2);
#pragma unroll
        for (int d = 32; d; d >>= 1) m = fmaxf(m, __shfl_xor(m, d, 64));
        float e1 = (tid < NODES) ? __expf(v1 - m) : 0.f;
        float e2 = (tid + 64 < NODES) ? __expf(v2 - m) : 0.f;
        float z = e1 + e2;
#pragma unroll
        for (int d = 32; d; d >>= 1) z += __shfl_xor(z, d, 64);
        float inv = 1.f / z;
        if (tid < NODES) gate[tid] = e1 * inv;
        if (tid + 64 < NODES) gate[tid + 64] = e2 * inv;
    }
    __syncthreads();

    // ---- parallel pool: 8 waves x 37 cols, partials in csr_val scratch ----
    {
        const int w = tid >> 6, l = tid & 63;
        if (l < 37) {
            float p = 0.f;
            for (int n = w; n < NODES; n += 8)
                p = fmaf(gate[n], sm.bufA[n * STRIDE + l], p);
            sm.csr_val[w * 37 + l] = p;
        }
    }
    __syncthreads();
    if (tid < 37) {
        float p = 0.f;
#pragma unroll
        for (int w = 0; w < 8; ++w) p += sm.csr_val[w * 37 + tid];
        out[g * 37 + tid] = p;
    }
}

extern "C" void kernel_launch(void* const* d_in, const int* in_sizes, int n_in,
                              void* d_out, int out_size, void* d_ws, size_t ws_size,
                              hipStream_t stream) {
    const float* x   = (const float*)d_in[0];
    const int*   src = (const int*)  d_in[1];
    const int*   dst = (const int*)  d_in[2];
    // d_in[3] = graph_ids (implicit: node / 100) -- unused
    const float* W0 = (const float*)d_in[4];  const float* b0 = (const float*)d_in[5];
    const float* W1 = (const float*)d_in[6];  const float* b1 = (const float*)d_in[7];
    const float* W2 = (const float*)d_in[8];  const float* b2 = (const float*)d_in[9];
    const float* W3 = (const float*)d_in[10]; const float* b3 = (const float*)d_in[11];
    const float* W4 = (const float*)d_in[12]; const float* b4 = (const float*)d_in[13];
    const float* gw = (const float*)d_in[14]; const float* gb = (const float*)d_in[15];
    float* out = (float*)d_out;

    // repack W into MFMA frag layout (max layer 45 tiles * 64 = 2880 thr)
    dim3 rg(12, 5, 1);
    repack_kernel<<<rg, 256, 0, stream>>>(W0, W1, W2, W3, W4);

    drug_graph_conv_kernel<<<5000, NTHR, 0, stream>>>(
        x, src, dst, b0, b1, b2, b3, b4, gw, gb, out);
}

// Round 4
// 817.015 us; speedup vs baseline: 5.3133x; 1.0356x over previous
//
#include <hip/hip_runtime.h>
#include <math.h>

// DrugGraphConv: 5000 graphs x 100 nodes x 400 edges, 5 TAGConv(K=2) layers
// DIMS = [74,70,65,60,55,37], gated softmax pooling per graph.
//
// R6/R8 (1.32ms): fp32-VALU dense, VALU-issue floor bound.
// R9 (846us, kernel 732us): dense on MFMA bf16 hi/lo split (AhBh+AhBl+AlBh,
// 3x mfma_f32_16x16x32_bf16). MfmaUtil 17%, VALUBusy 48.5%, VGPR 52.
// Remaining: ~30K cy/SIMD/graph stall -- 20 barriers w/ skew, kt loop
// unroll-1 walls (no cross-kt load hoisting), scalar x staging.
//
// R10: (a) buffer-flip: layer output goes to the OTHER buffer (dead after
// phase 2) -> drops the gblock2->store barrier (15 barriers, not 20) and
// overlaps stores with other waves' gblock2. Layers alternate src A/B;
// final h in bufB. (b) kt loop fully unrolled -> whole b-block is one BB,
// scheduler can prefetch next-kt h4/B loads under MFMAs. (c) x staging
// via dwordx4. No numerics change.

typedef __attribute__((ext_vector_type(8))) short bf16x8;
typedef __attribute__((ext_vector_type(4))) float f32x4;

constexpr int NODES  = 100;
constexpr int EDGES  = 400;
constexpr int STRIDE = 76;     // floats per LDS row (mult of 4)
constexpr int NTHR   = 512;

// packed W frags: per layer, per (b,kt,nt): 64 lanes x (8 bf16 hi + 8 bf16 lo)
// = 2048B per frag-tile. tiles: L0 3*3*5=45, L1 45, L2 36, L3 24, L4 18.
// u32 offsets: 0, 23040, 46080, 64512, 76800; total 86016 u32 = 344KB.
__device__ __align__(16) unsigned g_packW[86016];

struct __align__(16) Smem {
    float bufA[NODES * STRIDE];        // 30,400 B
    float bufB[NODES * STRIDE];        // 30,400 B
    float csr_val[EDGES];              //  1,600 B (nrm[src]; pool scratch later)
    unsigned short csr_src[EDGES];     //    800 B
    int   row_start[NODES + 1];        //    404 B
    int   cntg[NODES];                 //    400 B (cnt setup, gate after)
    float nrm[NODES];                  //    400 B  => 64,404 B (2 blocks/CU)
};

union FragU { unsigned u[4]; uint4 q; bf16x8 s; };

// truncation hi/lo bf16 split of a pair, packed little-endian (a -> low16).
__device__ __forceinline__ void split_pair(float a, float b,
                                           unsigned& h, unsigned& l) {
    unsigned ua = __float_as_uint(a), ub = __float_as_uint(b);
    unsigned ha = ua & 0xFFFF0000u,  hb = ub & 0xFFFF0000u;
    h = (ua >> 16) | hb;
    float ra = a - __uint_as_float(ha);
    float rb = b - __uint_as_float(hb);
    l = (__float_as_uint(ra) >> 16) | (__float_as_uint(rb) & 0xFFFF0000u);
}

// ---------------- repack kernel: W -> frag-ready bf16 hi/lo ----------------
template<int D_IN, int D_OUT, int KT, int NT, int WOFF_U32>
__device__ __forceinline__ void repack_layer(const float* __restrict__ W, int idx) {
    constexpr int TILES = 3 * KT * NT;
    if (idx >= TILES * 64) return;
    int lane = idx & 63, tile = idx >> 6;
    int nt = tile % NT;
    int kt = (tile / NT) % KT;
    int b  = tile / (NT * KT);
    int col = nt * 16 + (lane & 15);
    int kg  = (lane >> 4) << 2;
    float v[8];
#pragma unroll
    for (int i = 0; i < 8; ++i) {
        int k = kt * 32 + ((i >= 4) ? 16 : 0) + kg + (i & 3);
        float f = 0.f;
        if (k < D_IN && col < D_OUT) f = W[(b * D_IN + k) * D_OUT + col];
        v[i] = f;
    }
    unsigned hu[4], lu[4];
#pragma unroll
    for (int p = 0; p < 4; ++p) split_pair(v[2*p], v[2*p+1], hu[p], lu[p]);
    unsigned* dst = g_packW + WOFF_U32 + (tile * 64 + lane) * 8;
    *(uint4*)(dst)     = make_uint4(hu[0], hu[1], hu[2], hu[3]);
    *(uint4*)(dst + 4) = make_uint4(lu[0], lu[1], lu[2], lu[3]);
}

__global__ void repack_kernel(const float* __restrict__ W0, const float* __restrict__ W1,
                              const float* __restrict__ W2, const float* __restrict__ W3,
                              const float* __restrict__ W4) {
    int idx = blockIdx.x * 256 + threadIdx.x;
    switch (blockIdx.y) {
    case 0: repack_layer<74, 70, 3, 5,     0>(W0, idx); break;
    case 1: repack_layer<70, 65, 3, 5, 23040>(W1, idx); break;
    case 2: repack_layer<65, 60, 3, 4, 46080>(W2, idx); break;
    case 3: repack_layer<60, 55, 2, 4, 64512>(W3, idx); break;
    case 4: repack_layer<55, 37, 2, 3, 76800>(W4, idx); break;
    }
}

// ---------------- propagation (CSR gather, fp32 VALU) ----------------------
template<int D_IN>
__device__ __forceinline__ void propagate(const float* __restrict__ in,
                                          float* __restrict__ outb,
                                          const unsigned short* __restrict__ csr_src,
                                          const float* __restrict__ csr_val,
                                          const int* __restrict__ row_start,
                                          const float* __restrict__ nrm,
                                          int tid)
{
    constexpr int CH = (D_IN + 3) / 4;
    constexpr int R4 = STRIDE / 4;
    const float4* __restrict__ in4 = (const float4*)in;
    float4* __restrict__ out4 = (float4*)outb;

    for (int t = tid; t < NODES * CH; t += NTHR) {
        int n = t / CH;
        int c = t - n * CH;
        int beg = row_start[n], end = row_start[n + 1];
        float ax = 0.f, ay = 0.f, az = 0.f, aw = 0.f;
        int e = beg;
        for (; e + 3 < end; e += 4) {
            int   s0 = csr_src[e],     s1 = csr_src[e + 1];
            int   s2 = csr_src[e + 2], s3 = csr_src[e + 3];
            float c0 = csr_val[e],     c1 = csr_val[e + 1];
            float c2 = csr_val[e + 2], c3 = csr_val[e + 3];
            float4 v0 = in4[s0 * R4 + c];
            float4 v1 = in4[s1 * R4 + c];
            float4 v2 = in4[s2 * R4 + c];
            float4 v3 = in4[s3 * R4 + c];
            ax = fmaf(c0, v0.x, ax); ay = fmaf(c0, v0.y, ay);
            az = fmaf(c0, v0.z, az); aw = fmaf(c0, v0.w, aw);
            ax = fmaf(c1, v1.x, ax); ay = fmaf(c1, v1.y, ay);
            az = fmaf(c1, v1.z, az); aw = fmaf(c1, v1.w, aw);
            ax = fmaf(c2, v2.x, ax); ay = fmaf(c2, v2.y, ay);
            az = fmaf(c2, v2.z, az); aw = fmaf(c2, v2.w, aw);
            ax = fmaf(c3, v3.x, ax); ay = fmaf(c3, v3.y, ay);
            az = fmaf(c3, v3.z, az); aw = fmaf(c3, v3.w, aw);
        }
        for (; e < end; ++e) {
            int s = csr_src[e];
            float sc = csr_val[e];
            float4 v = in4[s * R4 + c];
            ax = fmaf(sc, v.x, ax); ay = fmaf(sc, v.y, ay);
            az = fmaf(sc, v.z, az); aw = fmaf(sc, v.w, aw);
        }
        float sn = nrm[n];
        float4 o = { ax * sn, ay * sn, az * sn, aw * sn };
        out4[n * R4 + c] = o;
    }
}

// ---------------- one feats-block of the dense matmul on MFMA --------------
template<int D_IN, int D_OUT, int KT, int NT, int WOFF_U32>
__device__ __forceinline__ void dense_block(const float* __restrict__ buf, int b,
                                            int mt, int lane, f32x4 (&acc)[NT]) {
    int row = mt * 16 + (lane & 15);
    row = row > NODES - 1 ? NODES - 1 : row;   // clamped rows masked at store
    const float* __restrict__ hrow = buf + row * STRIDE;
    const int kg = (lane >> 4) << 2;
    const uint4* __restrict__ wb =
        (const uint4*)(g_packW + WOFF_U32) + b * (KT * NT * 128) + lane * 2;
    // full unroll: whole b-block is one BB -> scheduler may hoist next-kt
    // h4 ds_reads and B-frag loads under the current kt's MFMAs.
#pragma unroll
    for (int kt = 0; kt < KT; ++kt) {
        // clamp so reads stay inside the row's 76 valid floats (finite data;
        // k>=D_IN lanes are killed by zeroed W rows, value irrelevant).
        int o0 = kt * 32 + kg;      if (o0 > 72) o0 = 72;
        int o1 = kt * 32 + 16 + kg; if (o1 > 72) o1 = 72;
        const float4 f0 = *(const float4*)(hrow + o0);   // ds_read_b128
        const float4 f1 = *(const float4*)(hrow + o1);
        FragU Ah, Al;
        split_pair(f0.x, f0.y, Ah.u[0], Al.u[0]);
        split_pair(f0.z, f0.w, Ah.u[1], Al.u[1]);
        split_pair(f1.x, f1.y, Ah.u[2], Al.u[2]);
        split_pair(f1.z, f1.w, Ah.u[3], Al.u[3]);
#pragma unroll
        for (int nt = 0; nt < NT; ++nt) {
            const uint4* __restrict__ wl = wb + (kt * NT + nt) * 128;
            FragU Bh, Bl;
            Bh.q = wl[0];            // global_load_dwordx4, L1/L2-resident
            Bl.q = wl[1];
            acc[nt] = __builtin_amdgcn_mfma_f32_16x16x32_bf16(Ah.s, Bh.s, acc[nt], 0, 0, 0);
            acc[nt] = __builtin_amdgcn_mfma_f32_16x16x32_bf16(Ah.s, Bl.s, acc[nt], 0, 0, 0);
            acc[nt] = __builtin_amdgcn_mfma_f32_16x16x32_bf16(Al.s, Bh.s, acc[nt], 0, 0, 0);
        }
    }
}

// ---------------- one TAGConv layer (src S, output -> T) -------------------
// Phase 1: gblock(S,0) || prop(S->T); B. Phase 2: gblock(T,1) || prop(T->S); B.
// Phase 3: gblock(S,2); store ReLU -> T (T dead after phase 2: its readers
// gblock(T,1)/prop(T->S) finished at barrier 2; nothing reads T in phase 3,
// so NO barrier between gblock2 and store). B. Next layer src = T.
// Stale cols >= D_OUT in T are killed by zero-padded W / never read by gate.
template<int D_IN, int D_OUT, int KT, int NT, int WOFF_U32>
__device__ __forceinline__ void tag_layer(Smem& sm,
                                          float* __restrict__ S,
                                          float* __restrict__ T,
                                          const float* __restrict__ Bv,
                                          int tid)
{
    const int wave  = __builtin_amdgcn_readfirstlane(tid >> 6); // uniform
    const int lane  = tid & 63;
    const bool m_act = wave < 7;      // 7 m-tiles cover 100 rows; wave7 prop-only

    f32x4 acc[NT];
#pragma unroll
    for (int nt = 0; nt < NT; ++nt) acc[nt] = (f32x4)(0.f);

    if (m_act) dense_block<D_IN, D_OUT, KT, NT, WOFF_U32>(S, 0, wave, lane, acc);
    propagate<D_IN>(S, T, sm.csr_src, sm.csr_val, sm.row_start, sm.nrm, tid);
    __syncthreads();
    if (m_act) dense_block<D_IN, D_OUT, KT, NT, WOFF_U32>(T, 1, wave, lane, acc);
    propagate<D_IN>(T, S, sm.csr_src, sm.csr_val, sm.row_start, sm.nrm, tid);
    __syncthreads();
    if (m_act) {
        dense_block<D_IN, D_OUT, KT, NT, WOFF_U32>(S, 2, wave, lane, acc);
        // C/D layout (verified): col = lane&15, row_in_tile = (lane>>4)*4 + r
#pragma unroll
        for (int nt = 0; nt < NT; ++nt) {
            int col = nt * 16 + (lane & 15);
            if (col < D_OUT) {
                float bias = Bv[col];
#pragma unroll
                for (int r = 0; r < 4; ++r) {
                    int row = wave * 16 + ((lane >> 4) << 2) + r;
                    if (row < NODES)
                        T[row * STRIDE + col] = fmaxf(acc[nt][r] + bias, 0.f);
                }
            }
        }
    }
    __syncthreads();
}

__global__ __launch_bounds__(NTHR, 4)  // VGPR<=128: keep 2 blocks/CU resident
void drug_graph_conv_kernel(
    const float* __restrict__ x,
    const int*   __restrict__ src,
    const int*   __restrict__ dst,
    const float* __restrict__ b0, const float* __restrict__ b1,
    const float* __restrict__ b2, const float* __restrict__ b3,
    const float* __restrict__ b4,
    const float* __restrict__ gate_w, const float* __restrict__ gate_b,
    float* __restrict__ out)
{
    __shared__ Smem sm;
    const int g     = blockIdx.x;
    const int tid   = threadIdx.x;
    const int nbase = g * NODES;

    // ---- stage x (100 x 74) into bufA at stride 76, dwordx4 loads ----
    // graph slab = 7400 floats, 16B-aligned (g*29,600B). float4s may straddle
    // row boundaries -> per-element row/col arithmetic (const-divisor mulshift).
    {
        const float4* __restrict__ x4 = (const float4*)(x + (size_t)nbase * 74);
        for (int t = tid; t < NODES * 74 / 4; t += NTHR) {   // 1850
            float4 v = x4[t];
            int idx = 4 * t;
#pragma unroll
            for (int k = 0; k < 4; ++k) {
                int ik = idx + k;
                int n  = ik / 74;
                int d  = ik - n * 74;
                float val = (k == 0) ? v.x : (k == 1) ? v.y : (k == 2) ? v.z : v.w;
                sm.bufA[n * STRIDE + d] = val;
            }
        }
    }
    for (int t = tid; t < NODES * 2; t += NTHR) {
        int n = t >> 1;
        sm.bufA[n * STRIDE + 74 + (t & 1)] = 0.f;
    }

    // ---- degree count ----
    if (tid < NODES) sm.cntg[tid] = 0;
    __syncthreads();
    int es = 0, ed = 0;
    const bool ethr = tid < EDGES;
    if (ethr) {
        es = src[g * EDGES + tid] - nbase;
        ed = dst[g * EDGES + tid] - nbase;
        atomicAdd(&sm.cntg[ed], 1);
    }
    __syncthreads();

    // ---- norm + CSR row offsets (wave-0 shuffle scan over 100 degrees) ----
    if (tid < NODES) sm.nrm[tid] = rsqrtf((float)max(sm.cntg[tid], 1));
    if (tid < 64) {
        int v1 = (tid < NODES) ? sm.cntg[tid] : 0;
        int l2 = tid + 64;
        int v2 = (l2 < NODES) ? sm.cntg[l2] : 0;
        int s1 = v1;
#pragma unroll
        for (int d = 1; d < 64; d <<= 1) {
            int t2 = __shfl_up(s1, d, 64);
            if (tid >= d) s1 += t2;
        }
        int tot1 = __shfl(s1, 63, 64);
        int s2 = v2;
#pragma unroll
        for (int d = 1; d < 64; d <<= 1) {
            int t2 = __shfl_up(s2, d, 64);
            if (tid >= d) s2 += t2;
        }
        s2 += tot1;
        if (tid == 0) sm.row_start[0] = 0;
        sm.row_start[tid + 1] = s1;
        if (l2 < NODES) sm.row_start[l2 + 1] = s2;
    }
    __syncthreads();
    if (tid < NODES) sm.cntg[tid] = 0;   // reuse as CSR fill cursor
    __syncthreads();
    if (ethr) {
        int pos = atomicAdd(&sm.cntg[ed], 1);
        int slot = sm.row_start[ed] + pos;
        sm.csr_src[slot] = (unsigned short)es;
        sm.csr_val[slot] = sm.nrm[es];
    }
    __syncthreads();

    // ---- 5 TAGConv layers (MFMA dense), src/dst buffers alternate ----
    tag_layer<74, 70, 3, 5,     0>(sm, sm.bufA, sm.bufB, b0, tid);
    tag_layer<70, 65, 3, 5, 23040>(sm, sm.bufB, sm.bufA, b1, tid);
    tag_layer<65, 60, 3, 4, 46080>(sm, sm.bufA, sm.bufB, b2, tid);
    tag_layer<60, 55, 2, 4, 64512>(sm, sm.bufB, sm.bufA, b3, tid);
    tag_layer<55, 37, 2, 3, 76800>(sm, sm.bufA, sm.bufB, b4, tid);
    // final h: 100 x 37 in bufB, stride 76

    // ---- gate + softmax + pool (gate stored in cntg as float) ----
    float* gate = (float*)sm.cntg;
    if (tid < NODES) {
        float s = gate_b[0];
#pragma unroll
        for (int k = 0; k < 37; ++k)
            s = fmaf(sm.bufB[tid * STRIDE + k], gate_w[k], s);
        gate[tid] = s;
    }
    __syncthreads();
    if (tid < 64) {
        float v1 = (tid < NODES) ? gate[tid] : -INFINITY;
        float v2 = (tid + 64 < NODES) ? gate[tid + 64] : -INFINITY;
        float m = fmaxf(v1, v2);
#pragma unroll
        for (int d = 32; d; d >>= 1) m = fmaxf(m, __shfl_xor(m, d, 64));
        float e1 = (tid < NODES) ? __expf(v1 - m) : 0.f;
        float e2 = (tid + 64 < NODES) ? __expf(v2 - m) : 0.f;
        float z = e1 + e2;
#pragma unroll
        for (int d = 32; d; d >>= 1) z += __shfl_xor(z, d, 64);
        float inv = 1.f / z;
        if (tid < NODES) gate[tid] = e1 * inv;
        if (tid + 64 < NODES) gate[tid + 64] = e2 * inv;
    }
    __syncthreads();

    // ---- parallel pool: 8 waves x 37 cols, partials in csr_val scratch ----
    {
        const int w = tid >> 6, l = tid & 63;
        if (l < 37) {
            float p = 0.f;
            for (int n = w; n < NODES; n += 8)
                p = fmaf(gate[n], sm.bufB[n * STRIDE + l], p);
            sm.csr_val[w * 37 + l] = p;
        }
    }
    __syncthreads();
    if (tid < 37) {
        float p = 0.f;
#pragma unroll
        for (int w = 0; w < 8; ++w) p += sm.csr_val[w * 37 + tid];
        out[g * 37 + tid] = p;
    }
}

extern "C" void kernel_launch(void* const* d_in, const int* in_sizes, int n_in,
                              void* d_out, int out_size, void* d_ws, size_t ws_size,
                              hipStream_t stream) {
    const float* x   = (const float*)d_in[0];
    const int*   src = (const int*)  d_in[1];
    const int*   dst = (const int*)  d_in[2];
    // d_in[3] = graph_ids (implicit: node / 100) -- unused
    const float* W0 = (const float*)d_in[4];  const float* b0 = (const float*)d_in[5];
    const float* W1 = (const float*)d_in[6];  const float* b1 = (const float*)d_in[7];
    const float* W2 = (const float*)d_in[8];  const float* b2 = (const float*)d_in[9];
    const float* W3 = (const float*)d_in[10]; const float* b3 = (const float*)d_in[11];
    const float* W4 = (const float*)d_in[12]; const float* b4 = (const float*)d_in[13];
    const float* gw = (const float*)d_in[14]; const float* gb = (const float*)d_in[15];
    float* out = (float*)d_out;

    // repack W into MFMA frag layout (max layer 45 tiles * 64 = 2880 thr)
    dim3 rg(12, 5, 1);
    repack_kernel<<<rg, 256, 0, stream>>>(W0, W1, W2, W3, W4);

    drug_graph_conv_kernel<<<5000, NTHR, 0, stream>>>(
        x, src, dst, b0, b1, b2, b3, b4, gw, gb, out);
}

// Round 5
// 807.937 us; speedup vs baseline: 5.3730x; 1.0112x over previous
//
#include <hip/hip_runtime.h>
#include <math.h>

// DrugGraphConv: 5000 graphs x 100 nodes x 400 edges, 5 TAGConv(K=2) layers
// DIMS = [74,70,65,60,55,37], gated softmax pooling per graph.
//
// R9 (732us): dense on MFMA bf16 hi/lo split (AhBh+AhBl+AlBh). R10 (701us):
// buffer-flip layer output (15 barriers), x dwordx4 staging. Counters:
// MfmaUtil 17.7, VALUBusy 46, Occ 44.7 (LDS 64,404B -> 2 blocks/CU), VGPR 52.
// ~36% stall; propagate is the largest VALU consumer; SIMD carrying wave 7
// (prop-only) idles at barriers while 2-dense-wave SIMDs are the wall.
//
// R11: propagate only:
// (a) dual-chunk tasks: each task does chunk pair (c0,c0+1) of one node --
//     CSR loads/addr/trip-divergence amortized over 2x payload, two
//     independent b128 streams per edge (ILP). Second chunk store guarded
//     (c1<CH) so rows never overflow; untouched pad chunks stay finite
//     (invariant dense already relies on: W rows k>=D_IN are zero).
// (b) weighted shares: wave 7 takes 14/56 of tasks, waves 0-6 take 6/56
//     (contiguous ranges) -- balances per-SIMD issue under both w%4 and
//     w>>1 wave->SIMD mappings since wave 7 is the unique dense-idle wave.

typedef __attribute__((ext_vector_type(8))) short bf16x8;
typedef __attribute__((ext_vector_type(4))) float f32x4;

constexpr int NODES  = 100;
constexpr int EDGES  = 400;
constexpr int STRIDE = 76;     // floats per LDS row (mult of 4)
constexpr int NTHR   = 512;

// packed W frags: per layer, per (b,kt,nt): 64 lanes x (8 bf16 hi + 8 bf16 lo)
// = 2048B per frag-tile. tiles: L0 3*3*5=45, L1 45, L2 36, L3 24, L4 18.
// u32 offsets: 0, 23040, 46080, 64512, 76800; total 86016 u32 = 344KB.
__device__ __align__(16) unsigned g_packW[86016];

struct __align__(16) Smem {
    float bufA[NODES * STRIDE];        // 30,400 B
    float bufB[NODES * STRIDE];        // 30,400 B
    float csr_val[EDGES];              //  1,600 B (nrm[src]; pool scratch later)
    unsigned short csr_src[EDGES];     //    800 B
    int   row_start[NODES + 1];        //    404 B
    int   cntg[NODES];                 //    400 B (cnt setup, gate after)
    float nrm[NODES];                  //    400 B  => 64,404 B (2 blocks/CU)
};

union FragU { unsigned u[4]; uint4 q; bf16x8 s; };

// truncation hi/lo bf16 split of a pair, packed little-endian (a -> low16).
__device__ __forceinline__ void split_pair(float a, float b,
                                           unsigned& h, unsigned& l) {
    unsigned ua = __float_as_uint(a), ub = __float_as_uint(b);
    unsigned ha = ua & 0xFFFF0000u,  hb = ub & 0xFFFF0000u;
    h = (ua >> 16) | hb;
    float ra = a - __uint_as_float(ha);
    float rb = b - __uint_as_float(hb);
    l = (__float_as_uint(ra) >> 16) | (__float_as_uint(rb) & 0xFFFF0000u);
}

// ---------------- repack kernel: W -> frag-ready bf16 hi/lo ----------------
template<int D_IN, int D_OUT, int KT, int NT, int WOFF_U32>
__device__ __forceinline__ void repack_layer(const float* __restrict__ W, int idx) {
    constexpr int TILES = 3 * KT * NT;
    if (idx >= TILES * 64) return;
    int lane = idx & 63, tile = idx >> 6;
    int nt = tile % NT;
    int kt = (tile / NT) % KT;
    int b  = tile / (NT * KT);
    int col = nt * 16 + (lane & 15);
    int kg  = (lane >> 4) << 2;
    float v[8];
#pragma unroll
    for (int i = 0; i < 8; ++i) {
        int k = kt * 32 + ((i >= 4) ? 16 : 0) + kg + (i & 3);
        float f = 0.f;
        if (k < D_IN && col < D_OUT) f = W[(b * D_IN + k) * D_OUT + col];
        v[i] = f;
    }
    unsigned hu[4], lu[4];
#pragma unroll
    for (int p = 0; p < 4; ++p) split_pair(v[2*p], v[2*p+1], hu[p], lu[p]);
    unsigned* dst = g_packW + WOFF_U32 + (tile * 64 + lane) * 8;
    *(uint4*)(dst)     = make_uint4(hu[0], hu[1], hu[2], hu[3]);
    *(uint4*)(dst + 4) = make_uint4(lu[0], lu[1], lu[2], lu[3]);
}

__global__ void repack_kernel(const float* __restrict__ W0, const float* __restrict__ W1,
                              const float* __restrict__ W2, const float* __restrict__ W3,
                              const float* __restrict__ W4) {
    int idx = blockIdx.x * 256 + threadIdx.x;
    switch (blockIdx.y) {
    case 0: repack_layer<74, 70, 3, 5,     0>(W0, idx); break;
    case 1: repack_layer<70, 65, 3, 5, 23040>(W1, idx); break;
    case 2: repack_layer<65, 60, 3, 4, 46080>(W2, idx); break;
    case 3: repack_layer<60, 55, 2, 4, 64512>(W3, idx); break;
    case 4: repack_layer<55, 37, 2, 3, 76800>(W4, idx); break;
    }
}

// ---------------- propagation (CSR gather, fp32 VALU) ----------------------
// out[n][:] = nrm[n] * sum_{e: dst==n} csr_val[e] * in[src_e][:]
// Dual-chunk tasks + weighted wave shares (see header comment).
template<int D_IN>
__device__ __forceinline__ void propagate(const float* __restrict__ in,
                                          float* __restrict__ outb,
                                          const unsigned short* __restrict__ csr_src,
                                          const float* __restrict__ csr_val,
                                          const int* __restrict__ row_start,
                                          const float* __restrict__ nrm,
                                          int wave, int lane)
{
    constexpr int CH = (D_IN + 3) / 4;            // valid float4 chunks
    constexpr int PR = (CH + 1) / 2;              // chunk-pairs per node
    constexpr int T  = NODES * PR;                // total tasks
    constexpr int R4 = STRIDE / 4;                // 19 float4 per row
    const float4* __restrict__ in4 = (const float4*)in;
    float4* __restrict__ out4 = (float4*)outb;

    // weighted contiguous partition: weights [6,6,6,6,6,6,6,14]/56
    const int lo = (T * (6 * wave)) / 56;                       // uniform
    const int hi = (wave == 7) ? T : (T * (6 * (wave + 1))) / 56;

    for (int t = lo + lane; t < hi; t += 64) {
        int n = t / PR;                           // const-divisor mulshift
        int p = t - n * PR;
        int c0 = 2 * p;
        int c1 = c0 + 1;
        bool has2 = (c1 < CH);                    // last pair of odd-CH nodes
        int c1r = has2 ? c1 : c0;                 // safe read index
        int beg = row_start[n], end = row_start[n + 1];
        float ax0 = 0.f, ay0 = 0.f, az0 = 0.f, aw0 = 0.f;
        float ax1 = 0.f, ay1 = 0.f, az1 = 0.f, aw1 = 0.f;
        int e = beg;
        for (; e + 3 < end; e += 4) {
            int   s0 = csr_src[e],     s1 = csr_src[e + 1];
            int   s2 = csr_src[e + 2], s3 = csr_src[e + 3];
            float q0 = csr_val[e],     q1 = csr_val[e + 1];
            float q2 = csr_val[e + 2], q3 = csr_val[e + 3];
            const float4* r0 = in4 + s0 * R4;
            const float4* r1 = in4 + s1 * R4;
            const float4* r2 = in4 + s2 * R4;
            const float4* r3 = in4 + s3 * R4;
            float4 u0 = r0[c0], v0 = r0[c1r];
            float4 u1 = r1[c0], v1 = r1[c1r];
            float4 u2 = r2[c0], v2 = r2[c1r];
            float4 u3 = r3[c0], v3 = r3[c1r];
            ax0 = fmaf(q0, u0.x, ax0); ay0 = fmaf(q0, u0.y, ay0);
            az0 = fmaf(q0, u0.z, az0); aw0 = fmaf(q0, u0.w, aw0);
            ax1 = fmaf(q0, v0.x, ax1); ay1 = fmaf(q0, v0.y, ay1);
            az1 = fmaf(q0, v0.z, az1); aw1 = fmaf(q0, v0.w, aw1);
            ax0 = fmaf(q1, u1.x, ax0); ay0 = fmaf(q1, u1.y, ay0);
            az0 = fmaf(q1, u1.z, az0); aw0 = fmaf(q1, u1.w, aw0);
            ax1 = fmaf(q1, v1.x, ax1); ay1 = fmaf(q1, v1.y, ay1);
            az1 = fmaf(q1, v1.z, az1); aw1 = fmaf(q1, v1.w, aw1);
            ax0 = fmaf(q2, u2.x, ax0); ay0 = fmaf(q2, u2.y, ay0);
            az0 = fmaf(q2, u2.z, az0); aw0 = fmaf(q2, u2.w, aw0);
            ax1 = fmaf(q2, v2.x, ax1); ay1 = fmaf(q2, v2.y, ay1);
            az1 = fmaf(q2, v2.z, az1); aw1 = fmaf(q2, v2.w, aw1);
            ax0 = fmaf(q3, u3.x, ax0); ay0 = fmaf(q3, u3.y, ay0);
            az0 = fmaf(q3, u3.z, az0); aw0 = fmaf(q3, u3.w, aw0);
            ax1 = fmaf(q3, v3.x, ax1); ay1 = fmaf(q3, v3.y, ay1);
            az1 = fmaf(q3, v3.z, az1); aw1 = fmaf(q3, v3.w, aw1);
        }
        for (; e < end; ++e) {
            int s = csr_src[e];
            float q = csr_val[e];
            const float4* r = in4 + s * R4;
            float4 u = r[c0], v = r[c1r];
            ax0 = fmaf(q, u.x, ax0); ay0 = fmaf(q, u.y, ay0);
            az0 = fmaf(q, u.z, az0); aw0 = fmaf(q, u.w, aw0);
            ax1 = fmaf(q, v.x, ax1); ay1 = fmaf(q, v.y, ay1);
            az1 = fmaf(q, v.z, az1); aw1 = fmaf(q, v.w, aw1);
        }
        float sn = nrm[n];
        float4 o0 = { ax0 * sn, ay0 * sn, az0 * sn, aw0 * sn };
        out4[n * R4 + c0] = o0;
        if (has2) {
            float4 o1 = { ax1 * sn, ay1 * sn, az1 * sn, aw1 * sn };
            out4[n * R4 + c1] = o1;
        }
    }
}

// ---------------- one feats-block of the dense matmul on MFMA --------------
template<int D_IN, int D_OUT, int KT, int NT, int WOFF_U32>
__device__ __forceinline__ void dense_block(const float* __restrict__ buf, int b,
                                            int mt, int lane, f32x4 (&acc)[NT]) {
    int row = mt * 16 + (lane & 15);
    row = row > NODES - 1 ? NODES - 1 : row;   // clamped rows masked at store
    const float* __restrict__ hrow = buf + row * STRIDE;
    const int kg = (lane >> 4) << 2;
    const uint4* __restrict__ wb =
        (const uint4*)(g_packW + WOFF_U32) + b * (KT * NT * 128) + lane * 2;
#pragma unroll
    for (int kt = 0; kt < KT; ++kt) {
        // clamp so reads stay inside the row's 76 valid floats (finite data;
        // k>=D_IN lanes are killed by zeroed W rows, value irrelevant).
        int o0 = kt * 32 + kg;      if (o0 > 72) o0 = 72;
        int o1 = kt * 32 + 16 + kg; if (o1 > 72) o1 = 72;
        const float4 f0 = *(const float4*)(hrow + o0);   // ds_read_b128
        const float4 f1 = *(const float4*)(hrow + o1);
        FragU Ah, Al;
        split_pair(f0.x, f0.y, Ah.u[0], Al.u[0]);
        split_pair(f0.z, f0.w, Ah.u[1], Al.u[1]);
        split_pair(f1.x, f1.y, Ah.u[2], Al.u[2]);
        split_pair(f1.z, f1.w, Ah.u[3], Al.u[3]);
#pragma unroll
        for (int nt = 0; nt < NT; ++nt) {
            const uint4* __restrict__ wl = wb + (kt * NT + nt) * 128;
            FragU Bh, Bl;
            Bh.q = wl[0];            // global_load_dwordx4, L1/L2-resident
            Bl.q = wl[1];
            acc[nt] = __builtin_amdgcn_mfma_f32_16x16x32_bf16(Ah.s, Bh.s, acc[nt], 0, 0, 0);
            acc[nt] = __builtin_amdgcn_mfma_f32_16x16x32_bf16(Ah.s, Bl.s, acc[nt], 0, 0, 0);
            acc[nt] = __builtin_amdgcn_mfma_f32_16x16x32_bf16(Al.s, Bh.s, acc[nt], 0, 0, 0);
        }
    }
}

// ---------------- one TAGConv layer (src S, output -> T) -------------------
// Phase 1: gblock(S,0) || prop(S->T); B. Phase 2: gblock(T,1) || prop(T->S); B.
// Phase 3: gblock(S,2); store ReLU -> T (T dead after phase 2; nothing reads
// T in phase 3, so no barrier between gblock2 and store). B. Next src = T.
// Stale cols >= D_OUT in T are killed by zero-padded W / never read by gate.
template<int D_IN, int D_OUT, int KT, int NT, int WOFF_U32>
__device__ __forceinline__ void tag_layer(Smem& sm,
                                          float* __restrict__ S,
                                          float* __restrict__ T,
                                          const float* __restrict__ Bv,
                                          int tid)
{
    const int wave  = __builtin_amdgcn_readfirstlane(tid >> 6); // uniform
    const int lane  = tid & 63;
    const bool m_act = wave < 7;      // 7 m-tiles cover 100 rows; wave7 prop-only

    f32x4 acc[NT];
#pragma unroll
    for (int nt = 0; nt < NT; ++nt) acc[nt] = (f32x4)(0.f);

    if (m_act) dense_block<D_IN, D_OUT, KT, NT, WOFF_U32>(S, 0, wave, lane, acc);
    propagate<D_IN>(S, T, sm.csr_src, sm.csr_val, sm.row_start, sm.nrm, wave, lane);
    __syncthreads();
    if (m_act) dense_block<D_IN, D_OUT, KT, NT, WOFF_U32>(T, 1, wave, lane, acc);
    propagate<D_IN>(T, S, sm.csr_src, sm.csr_val, sm.row_start, sm.nrm, wave, lane);
    __syncthreads();
    if (m_act) {
        dense_block<D_IN, D_OUT, KT, NT, WOFF_U32>(S, 2, wave, lane, acc);
        // C/D layout (verified): col = lane&15, row_in_tile = (lane>>4)*4 + r
#pragma unroll
        for (int nt = 0; nt < NT; ++nt) {
            int col = nt * 16 + (lane & 15);
            if (col < D_OUT) {
                float bias = Bv[col];
#pragma unroll
                for (int r = 0; r < 4; ++r) {
                    int row = wave * 16 + ((lane >> 4) << 2) + r;
                    if (row < NODES)
                        T[row * STRIDE + col] = fmaxf(acc[nt][r] + bias, 0.f);
                }
            }
        }
    }
    __syncthreads();
}

__global__ __launch_bounds__(NTHR, 4)  // VGPR<=128: keep 2 blocks/CU resident
void drug_graph_conv_kernel(
    const float* __restrict__ x,
    const int*   __restrict__ src,
    const int*   __restrict__ dst,
    const float* __restrict__ b0, const float* __restrict__ b1,
    const float* __restrict__ b2, const float* __restrict__ b3,
    const float* __restrict__ b4,
    const float* __restrict__ gate_w, const float* __restrict__ gate_b,
    float* __restrict__ out)
{
    __shared__ Smem sm;
    const int g     = blockIdx.x;
    const int tid   = threadIdx.x;
    const int nbase = g * NODES;

    // ---- stage x (100 x 74) into bufA at stride 76, dwordx4 loads ----
    {
        const float4* __restrict__ x4 = (const float4*)(x + (size_t)nbase * 74);
        for (int t = tid; t < NODES * 74 / 4; t += NTHR) {   // 1850
            float4 v = x4[t];
            int idx = 4 * t;
#pragma unroll
            for (int k = 0; k < 4; ++k) {
                int ik = idx + k;
                int n  = ik / 74;
                int d  = ik - n * 74;
                float val = (k == 0) ? v.x : (k == 1) ? v.y : (k == 2) ? v.z : v.w;
                sm.bufA[n * STRIDE + d] = val;
            }
        }
    }
    for (int t = tid; t < NODES * 2; t += NTHR) {
        int n = t >> 1;
        sm.bufA[n * STRIDE + 74 + (t & 1)] = 0.f;
    }

    // ---- degree count ----
    if (tid < NODES) sm.cntg[tid] = 0;
    __syncthreads();
    int es = 0, ed = 0;
    const bool ethr = tid < EDGES;
    if (ethr) {
        es = src[g * EDGES + tid] - nbase;
        ed = dst[g * EDGES + tid] - nbase;
        atomicAdd(&sm.cntg[ed], 1);
    }
    __syncthreads();

    // ---- norm + CSR row offsets (wave-0 shuffle scan over 100 degrees) ----
    if (tid < NODES) sm.nrm[tid] = rsqrtf((float)max(sm.cntg[tid], 1));
    if (tid < 64) {
        int v1 = (tid < NODES) ? sm.cntg[tid] : 0;
        int l2 = tid + 64;
        int v2 = (l2 < NODES) ? sm.cntg[l2] : 0;
        int s1 = v1;
#pragma unroll
        for (int d = 1; d < 64; d <<= 1) {
            int t2 = __shfl_up(s1, d, 64);
            if (tid >= d) s1 += t2;
        }
        int tot1 = __shfl(s1, 63, 64);
        int s2 = v2;
#pragma unroll
        for (int d = 1; d < 64; d <<= 1) {
            int t2 = __shfl_up(s2, d, 64);
            if (tid >= d) s2 += t2;
        }
        s2 += tot1;
        if (tid == 0) sm.row_start[0] = 0;
        sm.row_start[tid + 1] = s1;
        if (l2 < NODES) sm.row_start[l2 + 1] = s2;
    }
    __syncthreads();
    if (tid < NODES) sm.cntg[tid] = 0;   // reuse as CSR fill cursor
    __syncthreads();
    if (ethr) {
        int pos = atomicAdd(&sm.cntg[ed], 1);
        int slot = sm.row_start[ed] + pos;
        sm.csr_src[slot] = (unsigned short)es;
        sm.csr_val[slot] = sm.nrm[es];
    }
    __syncthreads();

    // ---- 5 TAGConv layers (MFMA dense), src/dst buffers alternate ----
    tag_layer<74, 70, 3, 5,     0>(sm, sm.bufA, sm.bufB, b0, tid);
    tag_layer<70, 65, 3, 5, 23040>(sm, sm.bufB, sm.bufA, b1, tid);
    tag_layer<65, 60, 3, 4, 46080>(sm, sm.bufA, sm.bufB, b2, tid);
    tag_layer<60, 55, 2, 4, 64512>(sm, sm.bufB, sm.bufA, b3, tid);
    tag_layer<55, 37, 2, 3, 76800>(sm, sm.bufA, sm.bufB, b4, tid);
    // final h: 100 x 37 in bufB, stride 76

    // ---- gate + softmax + pool (gate stored in cntg as float) ----
    float* gate = (float*)sm.cntg;
    if (tid < NODES) {
        float s = gate_b[0];
#pragma unroll
        for (int k = 0; k < 37; ++k)
            s = fmaf(sm.bufB[tid * STRIDE + k], gate_w[k], s);
        gate[tid] = s;
    }
    __syncthreads();
    if (tid < 64) {
        float v1 = (tid < NODES) ? gate[tid] : -INFINITY;
        float v2 = (tid + 64 < NODES) ? gate[tid + 64] : -INFINITY;
        float m = fmaxf(v1, v2);
#pragma unroll
        for (int d = 32; d; d >>= 1) m = fmaxf(m, __shfl_xor(m, d, 64));
        float e1 = (tid < NODES) ? __expf(v1 - m) : 0.f;
        float e2 = (tid + 64 < NODES) ? __expf(v2 - m) : 0.f;
        float z = e1 + e2;
#pragma unroll
        for (int d = 32; d; d >>= 1) z += __shfl_xor(z, d, 64);
        float inv = 1.f / z;
        if (tid < NODES) gate[tid] = e1 * inv;
        if (tid + 64 < NODES) gate[tid + 64] = e2 * inv;
    }
    __syncthreads();

    // ---- parallel pool: 8 waves x 37 cols, partials in csr_val scratch ----
    {
        const int w = tid >> 6, l = tid & 63;
        if (l < 37) {
            float p = 0.f;
            for (int n = w; n < NODES; n += 8)
                p = fmaf(gate[n], sm.bufB[n * STRIDE + l], p);
            sm.csr_val[w * 37 + l] = p;
        }
    }
    __syncthreads();
    if (tid < 37) {
        float p = 0.f;
#pragma unroll
        for (int w = 0; w < 8; ++w) p += sm.csr_val[w * 37 + tid];
        out[g * 37 + tid] = p;
    }
}

extern "C" void kernel_launch(void* const* d_in, const int* in_sizes, int n_in,
                              void* d_out, int out_size, void* d_ws, size_t ws_size,
                              hipStream_t stream) {
    const float* x   = (const float*)d_in[0];
    const int*   src = (const int*)  d_in[1];
    const int*   dst = (const int*)  d_in[2];
    // d_in[3] = graph_ids (implicit: node / 100) -- unused
    const float* W0 = (const float*)d_in[4];  const float* b0 = (const float*)d_in[5];
    const float* W1 = (const float*)d_in[6];  const float* b1 = (const float*)d_in[7];
    const float* W2 = (const float*)d_in[8];  const float* b2 = (const float*)d_in[9];
    const float* W3 = (const float*)d_in[10]; const float* b3 = (const float*)d_in[11];
    const float* W4 = (const float*)d_in[12]; const float* b4 = (const float*)d_in[13];
    const float* gw = (const float*)d_in[14]; const float* gb = (const float*)d_in[15];
    float* out = (float*)d_out;

    // repack W into MFMA frag layout (max layer 45 tiles * 64 = 2880 thr)
    dim3 rg(12, 5, 1);
    repack_kernel<<<rg, 256, 0, stream>>>(W0, W1, W2, W3, W4);

    drug_graph_conv_kernel<<<5000, NTHR, 0, stream>>>(
        x, src, dst, b0, b1, b2, b3, b4, gw, gb, out);
}